// Round 17
// baseline (1648.301 us; speedup 1.0000x reference)
//
#include <hip/hip_runtime.h>
#include <stdint.h>

#define M_DIM 8192
#define N_DIM 11008
#define K_DIM 4096

#define BM 256
#define BN 256
#define BK 64                    // i8: 64 B per row per tile
#define NT (K_DIM / BK)          // 64 K-tiles
#define GRID_M (M_DIM / BM)      // 32
#define GRID_N (N_DIM / BN)      // 43
#define NWG (GRID_M * GRID_N)    // 1376 (divisible by 8)

#define BUF (BM * BK)            // 16384 B per tile-buffer per matrix
#define NRING 4                  // ring-4: LDS = 4*2*16384 = 131072 B (128 KiB)

typedef int i32x4 __attribute__((ext_vector_type(4)));

__device__ __forceinline__ void gload16(const int8_t* src, int8_t* dst) {
    __builtin_amdgcn_global_load_lds(
        (const __attribute__((address_space(1))) uint32_t*)src,
        (__attribute__((address_space(3))) uint32_t*)dst, 16, 0, 0);
}

// ---------- pre-pass 1: per-row (token) absmax quant of x -> i8 + inv scale ----------

__global__ __launch_bounds__(256) void quant_x_kernel(
    const float* __restrict__ x, int8_t* __restrict__ xq, float* __restrict__ sinv)
{
    const int wave = blockIdx.x * 4 + (threadIdx.x >> 6);
    const int lane = threadIdx.x & 63;
    const float* row = x + (size_t)wave * K_DIM;

    float4 v[16];
    float mx = 0.0f;
    #pragma unroll
    for (int j = 0; j < 16; ++j) {
        v[j] = *(const float4*)(row + (j * 64 + lane) * 4);
        mx = fmaxf(mx, fmaxf(fmaxf(fabsf(v[j].x), fabsf(v[j].y)),
                             fmaxf(fabsf(v[j].z), fabsf(v[j].w))));
    }
    #pragma unroll
    for (int off = 32; off > 0; off >>= 1)
        mx = fmaxf(mx, __shfl_xor(mx, off));
    if (mx < 1e-30f) mx = 1e-30f;
    const float s = 127.0f / mx;

    int8_t* orow = xq + (size_t)wave * K_DIM;
    #pragma unroll
    for (int j = 0; j < 16; ++j) {
        int a = (int)__builtin_rintf(v[j].x * s);
        int b = (int)__builtin_rintf(v[j].y * s);
        int c = (int)__builtin_rintf(v[j].z * s);
        int d = (int)__builtin_rintf(v[j].w * s);
        uint32_t p = (uint32_t)(a & 0xFF) | ((uint32_t)(b & 0xFF) << 8) |
                     ((uint32_t)(c & 0xFF) << 16) | ((uint32_t)(d & 0xFF) << 24);
        *(uint32_t*)(orow + (j * 64 + lane) * 4) = p;
    }
    if (lane == 0) sinv[wave] = mx / 127.0f;
}

// ---------- pre-pass 2: f32 w -> sign(w) in i8 (exact {-1,0,+1}) ----------

__global__ __launch_bounds__(256) void sign_w_kernel(
    const float* __restrict__ w, int8_t* __restrict__ wq, long long n16)
{
    long long i = (long long)blockIdx.x * blockDim.x + threadIdx.x;
    const long long stride = (long long)gridDim.x * blockDim.x;
    for (; i < n16; i += stride) {
        const float* src = w + i * 16;
        uint32_t pk[4];
        #pragma unroll
        for (int q = 0; q < 4; ++q) {
            float4 f = *(const float4*)(src + q * 4);
            int a = (f.x > 0.f) ? 1 : ((f.x < 0.f) ? -1 : 0);
            int b = (f.y > 0.f) ? 1 : ((f.y < 0.f) ? -1 : 0);
            int c = (f.z > 0.f) ? 1 : ((f.z < 0.f) ? -1 : 0);
            int d = (f.w > 0.f) ? 1 : ((f.w < 0.f) ? -1 : 0);
            pk[q] = (uint32_t)(a & 0xFF) | ((uint32_t)(b & 0xFF) << 8) |
                    ((uint32_t)(c & 0xFF) << 16) | ((uint32_t)(d & 0xFF) << 24);
        }
        *(i32x4*)(wq + i * 16) = (i32x4){(int)pk[0], (int)pk[1], (int)pk[2], (int)pk[3]};
    }
}

// ---------- main GEMM (i8): 256x256, BK=64, 16 waves, RING-4, STAGGERED
// READ BURSTS (r16 post-mortem): at 4 waves/SIMD the tile still measured
// 2412 cy vs DS-floor 1536 — post-barrier all 16 waves burst 128 ds_reads;
// round-robin DS service returns every wave's LAST read near the END of the
// ~1536-cy drain, and in-order issue parks all waves in their read stretch ->
// burst phase and MFMA phase still alternate. Two fixes, same sync structure:
//  (1) consumption-ordered reads (B-frags first): MFMA m0 needs br0-3+ar0 =
//      reads 1-5 of 8, so the compiler's fine-grained lgkm lets compute start
//      at ~5/8 of the wave's drain instead of after br3 (last in r16).
//  (2) per-arm issue stagger: wave-uniform delay of wr*32 s_nop(7) iterations
//      (~384 cy per step; wr=wid>>2 -> distinct phase for each of the 4 waves
//      on a SIMD) before the read burst. Read bursts enter the DS queue in 4
//      staggered groups matching the ~384-cy/arm drain rate; the MFMA pipe is
//      fed continuously by whichever arm has its frags ready.
// Delay is pure scalar nops (no pipe use; other waves issue freely); per-wave
// vmcnt/lgkm counts and barrier placement identical to r16 (proven).
//
// body(t): [stagger nops] ; 8 frag reads (br first) ; stage(t+3) ;
//          16 MFMA ; vmcnt ladder (4/2/0) ; s_barrier.
// Ring-4 WAR/RAW audit unchanged from r16 (absmax 3.75 verified).

__global__ __launch_bounds__(1024, 4) void ternary_gemm_i8(
    const int8_t* __restrict__ A, const int8_t* __restrict__ B,
    const float* __restrict__ bias, const float* __restrict__ sinv,
    float* __restrict__ out)
{
    extern __shared__ int8_t lds[];
    int8_t* As = lds;                   // [NRING][BUF]
    int8_t* Bs = lds + NRING * BUF;     // [NRING][BUF]

    const int tid  = threadIdx.x;
    const int lane = tid & 63;
    const int wid  = tid >> 6;        // 0..15
    const int wr   = wid >> 2;        // 0..3  (64-row slab; also SIMD-phase)
    const int wc   = wid & 3;         // 0..3  (64-col slab)
    const int l15  = lane & 15;
    const int l4   = lane >> 4;       // 0..3

    // T1: bijective XCD swizzle (NWG % 8 == 0), bn-minor for A-panel L2 reuse
    const int bid = blockIdx.x;
    const int swz = (bid & 7) * (NWG / 8) + (bid >> 3);
    const int bm  = swz / GRID_N;
    const int bn  = swz % GRID_N;
    const long brow = (long)bm * BM;
    const long bcol = (long)bn * BN;

    // ---- staging addressing: 1024 threads cover 256 rows x 4 slots;
    // row = tid>>2, LDS dest linear (tid*16), global src slot inverse-swizzled
    const int rowt = tid >> 2;                        // 0..255
    const int ssrc = (tid & 3) ^ ((tid >> 3) & 3);
    const int8_t* pA = A + (size_t)(brow + rowt) * K_DIM + ssrc * 16;
    const int8_t* pB = B + (size_t)(bcol + rowt) * K_DIM + ssrc * 16;

    auto stageAB = [&](int t, int bslot) {
        gload16(pA + (size_t)t * BK, As + bslot * BUF + tid * 16);
        gload16(pB + (size_t)t * BK, Bs + bslot * BUF + tid * 16);
    };

    // ---- fragment read addressing (r6-verified swizzle) ----
    const int slot = l4 ^ ((l15 >> 1) & 3);
    const int aOff = (wr * 64 + l15) * 64 + slot * 16;   // + m*1024 (m*16 rows)
    const int bOff = (wc * 64 + l15) * 64 + slot * 16;   // + n*1024

    // per-arm stagger count (wave-uniform): wr * 32 iterations x ~12 cy
    const int dly = wr * 32;

    i32x4 acc[4][4];
    #pragma unroll
    for (int m = 0; m < 4; ++m)
        #pragma unroll
        for (int n = 0; n < 4; ++n) acc[m][n] = (i32x4){0, 0, 0, 0};

    // ---- prologue: stage tiles 0,1,2; vmcnt(4) [tile 0 landed]; barrier ----
    stageAB(0, 0); stageAB(1, 1); stageAB(2, 2);
    asm volatile("s_waitcnt vmcnt(4)" ::: "memory");
    __builtin_amdgcn_s_barrier();
    __builtin_amdgcn_sched_barrier(0);

    for (int t = 0; t < NT; ++t) {
        const int b = t & 3;

        // (2) staggered entry into the read burst (scalar nops, no pipe use)
        for (int i = 0; i < dly; ++i) asm volatile("s_nop 7");
        __builtin_amdgcn_sched_barrier(0);

        // (1) consumption-ordered frag reads: B first, then A
        i32x4 ar[4], br[4];
        #pragma unroll
        for (int n = 0; n < 4; ++n)
            br[n] = *(const i32x4*)(Bs + b * BUF + n * 1024 + bOff);
        #pragma unroll
        for (int m = 0; m < 4; ++m)
            ar[m] = *(const i32x4*)(As + b * BUF + m * 1024 + aOff);

        // stage(t+3) -> slot (t-1)%4 (WAR-safe: readers done pre-boundary(t-1))
        if (t + 3 < NT) stageAB(t + 3, (t + 3) & 3);

        __builtin_amdgcn_s_setprio(1);
        #pragma unroll
        for (int m = 0; m < 4; ++m)
            #pragma unroll
            for (int n = 0; n < 4; ++n)
                acc[m][n] = __builtin_amdgcn_mfma_i32_16x16x64_i8(ar[m], br[n], acc[m][n], 0, 0, 0);
        __builtin_amdgcn_s_setprio(0);
        __builtin_amdgcn_sched_barrier(0);

        // boundary: vmcnt ladder (certify tile t+1) + barrier
        if (t <= NT - 4)      { asm volatile("s_waitcnt vmcnt(4)" ::: "memory"); }
        else if (t == NT - 3) { asm volatile("s_waitcnt vmcnt(2)" ::: "memory"); }
        else                  { asm volatile("s_waitcnt vmcnt(0)" ::: "memory"); }
        __builtin_amdgcn_s_barrier();
        __builtin_amdgcn_sched_barrier(0);
    }

    // ---- epilogue: out = acc * sinv[row] + bias[col] ----
    // C/D layout (dtype-independent, m121-128): col=lane&15, row=(lane>>4)*4+reg
    int   cols[4];
    float bv[4];
    #pragma unroll
    for (int n = 0; n < 4; ++n) {
        cols[n] = (int)bcol + wc * 64 + n * 16 + l15;
        bv[n] = bias[cols[n]];
    }
    #pragma unroll
    for (int m = 0; m < 4; ++m) {
        const size_t row0 = (size_t)brow + wr * 64 + m * 16 + l4 * 4;
        float s0 = sinv[row0], s1 = sinv[row0 + 1], s2 = sinv[row0 + 2], s3 = sinv[row0 + 3];
        #pragma unroll
        for (int n = 0; n < 4; ++n) {
            out[(row0 + 0) * N_DIM + cols[n]] = (float)acc[m][n][0] * s0 + bv[n];
            out[(row0 + 1) * N_DIM + cols[n]] = (float)acc[m][n][1] * s1 + bv[n];
            out[(row0 + 2) * N_DIM + cols[n]] = (float)acc[m][n][2] * s2 + bv[n];
            out[(row0 + 3) * N_DIM + cols[n]] = (float)acc[m][n][3] * s3 + bv[n];
        }
    }
}

// ---------- fallback (only if workspace too small): correct but slow ----------

__global__ void naive_kernel(const float* __restrict__ x, const float* __restrict__ w,
                             const float* __restrict__ bias, float* __restrict__ out) {
    long long o = (long long)blockIdx.x * blockDim.x + threadIdx.x;
    if (o >= (long long)M_DIM * N_DIM) return;
    int row = (int)(o / N_DIM), col = (int)(o % N_DIM);
    float s = 0.0f;
    const float* xr = x + (size_t)row * K_DIM;
    const float* wr = w + (size_t)col * K_DIM;
    for (int k = 0; k < K_DIM; ++k) {
        float wv = wr[k];
        s += (wv > 0.0f) ? xr[k] : ((wv < 0.0f) ? -xr[k] : 0.0f);
    }
    out[o] = s + bias[col];
}

// ---------- launch ----------

extern "C" void kernel_launch(void* const* d_in, const int* in_sizes, int n_in,
                              void* d_out, int out_size, void* d_ws, size_t ws_size,
                              hipStream_t stream) {
    const float* x    = (const float*)d_in[0];
    const float* w    = (const float*)d_in[1];
    const float* bias = (const float*)d_in[2];
    float* out        = (float*)d_out;

    const size_t xq_bytes = (size_t)M_DIM * K_DIM;        // 33.6 MB
    const size_t wq_bytes = (size_t)N_DIM * K_DIM;        // 45.1 MB
    const size_t si_bytes = (size_t)M_DIM * sizeof(float);

    if (ws_size >= xq_bytes + wq_bytes + si_bytes) {
        int8_t* xq   = (int8_t*)d_ws;
        int8_t* wq   = (int8_t*)((char*)d_ws + xq_bytes);
        float*  sinv = (float*)((char*)d_ws + xq_bytes + wq_bytes);

        quant_x_kernel<<<M_DIM / 4, 256, 0, stream>>>(x, xq, sinv);
        const long long n16 = ((long long)N_DIM * K_DIM) / 16;
        sign_w_kernel<<<2048, 256, 0, stream>>>(w, wq, n16);

        const int lds_bytes = NRING * 2 * BUF;   // 131072
        hipFuncSetAttribute(reinterpret_cast<const void*>(ternary_gemm_i8),
                            hipFuncAttributeMaxDynamicSharedMemorySize, lds_bytes);
        ternary_gemm_i8<<<NWG, 1024, lds_bytes, stream>>>(xq, wq, bias, sinv, out);
    } else {
        const long long total = (long long)M_DIM * N_DIM;
        naive_kernel<<<(int)((total + 255) / 256), 256, 0, stream>>>(x, w, bias, out);
    }
}

// Round 18
// 507.571 us; speedup vs baseline: 3.2474x; 3.2474x over previous
//
#include <hip/hip_runtime.h>
#include <stdint.h>

#define M_DIM 8192
#define N_DIM 11008
#define K_DIM 4096

#define BM 256
#define BN 256
#define BK 64                    // i8: 64 B per row per tile
#define NT (K_DIM / BK)          // 64 K-tiles
#define GRID_M (M_DIM / BM)      // 32
#define GRID_N (N_DIM / BN)      // 43
#define NWG (GRID_M * GRID_N)    // 1376 (divisible by 8)

#define BUF (BM * BK)            // 16384 B per tile-buffer per matrix
#define NRING 4                  // ring-4: LDS = 4*2*16384 = 131072 B (128 KiB)

typedef int i32x4 __attribute__((ext_vector_type(4)));
typedef int i32x16 __attribute__((ext_vector_type(16)));

__device__ __forceinline__ void gload16(const int8_t* src, int8_t* dst) {
    __builtin_amdgcn_global_load_lds(
        (const __attribute__((address_space(1))) uint32_t*)src,
        (__attribute__((address_space(3))) uint32_t*)dst, 16, 0, 0);
}

// ---------- pre-pass 1: per-row (token) absmax quant of x -> i8 + inv scale ----------

__global__ __launch_bounds__(256) void quant_x_kernel(
    const float* __restrict__ x, int8_t* __restrict__ xq, float* __restrict__ sinv)
{
    const int wave = blockIdx.x * 4 + (threadIdx.x >> 6);
    const int lane = threadIdx.x & 63;
    const float* row = x + (size_t)wave * K_DIM;

    float4 v[16];
    float mx = 0.0f;
    #pragma unroll
    for (int j = 0; j < 16; ++j) {
        v[j] = *(const float4*)(row + (j * 64 + lane) * 4);
        mx = fmaxf(mx, fmaxf(fmaxf(fabsf(v[j].x), fabsf(v[j].y)),
                             fmaxf(fabsf(v[j].z), fabsf(v[j].w))));
    }
    #pragma unroll
    for (int off = 32; off > 0; off >>= 1)
        mx = fmaxf(mx, __shfl_xor(mx, off));
    if (mx < 1e-30f) mx = 1e-30f;
    const float s = 127.0f / mx;

    int8_t* orow = xq + (size_t)wave * K_DIM;
    #pragma unroll
    for (int j = 0; j < 16; ++j) {
        int a = (int)__builtin_rintf(v[j].x * s);
        int b = (int)__builtin_rintf(v[j].y * s);
        int c = (int)__builtin_rintf(v[j].z * s);
        int d = (int)__builtin_rintf(v[j].w * s);
        uint32_t p = (uint32_t)(a & 0xFF) | ((uint32_t)(b & 0xFF) << 8) |
                     ((uint32_t)(c & 0xFF) << 16) | ((uint32_t)(d & 0xFF) << 24);
        *(uint32_t*)(orow + (j * 64 + lane) * 4) = p;
    }
    if (lane == 0) sinv[wave] = mx / 127.0f;
}

// ---------- pre-pass 2: f32 w -> sign(w) in i8 (exact {-1,0,+1}) ----------

__global__ __launch_bounds__(256) void sign_w_kernel(
    const float* __restrict__ w, int8_t* __restrict__ wq, long long n16)
{
    long long i = (long long)blockIdx.x * blockDim.x + threadIdx.x;
    const long long stride = (long long)gridDim.x * blockDim.x;
    for (; i < n16; i += stride) {
        const float* src = w + i * 16;
        uint32_t pk[4];
        #pragma unroll
        for (int q = 0; q < 4; ++q) {
            float4 f = *(const float4*)(src + q * 4);
            int a = (f.x > 0.f) ? 1 : ((f.x < 0.f) ? -1 : 0);
            int b = (f.y > 0.f) ? 1 : ((f.y < 0.f) ? -1 : 0);
            int c = (f.z > 0.f) ? 1 : ((f.z < 0.f) ? -1 : 0);
            int d = (f.w > 0.f) ? 1 : ((f.w < 0.f) ? -1 : 0);
            pk[q] = (uint32_t)(a & 0xFF) | ((uint32_t)(b & 0xFF) << 8) |
                    ((uint32_t)(c & 0xFF) << 16) | ((uint32_t)(d & 0xFF) << 24);
        }
        *(i32x4*)(wq + i * 16) = (i32x4){(int)pk[0], (int)pk[1], (int)pk[2], (int)pk[3]};
    }
}

// ---------- main GEMM (i8): 256x256, BK=64, 16 waves, RING-4, 32x32x32 MFMA.
// r17 post-mortem: nop-stagger structurally impossible under per-tile barriers
// (delay re-added to critical path each tile) -> reverted to r16 (proven 386us
// GEMM). This round: switch 16x16x64 -> 32x32x32 i8 MFMA:
//   rate 3944 -> 4404 TOPS (m16/m55, +11.7%); MFMA insts HALVED (8/wave/tile,
//   2x ops each) -> less issue pressure alongside DS reads; identical frag
//   bytes (8 x b128/wave/tile), identical acc regs (64).
// A/B layout (K-doubling analogy from m74/m101-verified 32x32x16 bf16, same
// analogy that made i8 16x16x64 work first-try in r5):
//   A: row = l&31 (+ mi*32 + wr*64), k = ks*32 + (l>>5)*16 + [0..16)
//   C/D (verified, dtype-indep): col = l&31, row = (reg&3)+8*(reg>>2)+4*(l>>5)
// Staging, LDS image, swizzle involution, ring-4, vmcnt ladder (4/2/0),
// one barrier/tile: byte-identical to r16. Frag-read slots re-derived:
//   slot(ks) = (ks*2 + (l>>5)) ^ ((l31>>1)&3)   [same (row>>1)&3 involution]
// Bank behavior of 32-row reads not derivable from docs -> SQ_LDS_BANK_CONFLICT
// adjudicates; if >>1e6, revert to r16.
// Also: stage issued BEFORE frag reads (DMA enters VMEM queue first, lands
// under MFMA); reads in consumption order (ks0 B,A then ks1 B,A).

__global__ __launch_bounds__(1024, 4) void ternary_gemm_i8(
    const int8_t* __restrict__ A, const int8_t* __restrict__ B,
    const float* __restrict__ bias, const float* __restrict__ sinv,
    float* __restrict__ out)
{
    extern __shared__ int8_t lds[];
    int8_t* As = lds;                   // [NRING][BUF]
    int8_t* Bs = lds + NRING * BUF;     // [NRING][BUF]

    const int tid  = threadIdx.x;
    const int lane = tid & 63;
    const int wid  = tid >> 6;        // 0..15
    const int wr   = wid >> 2;        // 0..3  (64-row slab)
    const int wc   = wid & 3;         // 0..3  (64-col slab)
    const int l31  = lane & 31;
    const int l5   = lane >> 5;       // 0..1

    // T1: bijective XCD swizzle (NWG % 8 == 0), bn-minor for A-panel L2 reuse
    const int bid = blockIdx.x;
    const int swz = (bid & 7) * (NWG / 8) + (bid >> 3);
    const int bm  = swz / GRID_N;
    const int bn  = swz % GRID_N;
    const long brow = (long)bm * BM;
    const long bcol = (long)bn * BN;

    // ---- staging addressing (r16-identical): row = tid>>2, LDS dest linear
    // (tid*16), global src slot inverse-swizzled ----
    const int rowt = tid >> 2;                        // 0..255
    const int ssrc = (tid & 3) ^ ((tid >> 3) & 3);
    const int8_t* pA = A + (size_t)(brow + rowt) * K_DIM + ssrc * 16;
    const int8_t* pB = B + (size_t)(bcol + rowt) * K_DIM + ssrc * 16;

    auto stageAB = [&](int t, int bslot) {
        gload16(pA + (size_t)t * BK, As + bslot * BUF + tid * 16);
        gload16(pB + (size_t)t * BK, Bs + bslot * BUF + tid * 16);
    };

    // ---- fragment read addressing (32x32 pattern, same swizzle involution) ----
    const int sw  = (l31 >> 1) & 3;
    const int sA0 = ((0 * 2 + l5) ^ sw) * 16;   // ks=0 slot byte-offset
    const int sA1 = ((1 * 2 + l5) ^ sw) * 16;   // ks=1
    const int aRow = (wr * 64 + l31) * 64;      // + mi*2048
    const int bRow = (wc * 64 + l31) * 64;      // + ni*2048

    i32x16 acc[2][2];
    #pragma unroll
    for (int mi = 0; mi < 2; ++mi)
        #pragma unroll
        for (int ni = 0; ni < 2; ++ni)
            #pragma unroll
            for (int r = 0; r < 16; ++r) acc[mi][ni][r] = 0;

    // ---- prologue: stage tiles 0,1,2; vmcnt(4) [tile 0 landed]; barrier ----
    stageAB(0, 0); stageAB(1, 1); stageAB(2, 2);
    asm volatile("s_waitcnt vmcnt(4)" ::: "memory");
    __builtin_amdgcn_s_barrier();
    __builtin_amdgcn_sched_barrier(0);

    for (int t = 0; t < NT; ++t) {
        const int b = t & 3;
        const int8_t* Ab = As + b * BUF;
        const int8_t* Bb = Bs + b * BUF;

        // stage(t+3) first: DMA enters VMEM queue ahead of frag reads
        if (t + 3 < NT) stageAB(t + 3, (t + 3) & 3);

        // 8 frag reads, consumption order (ks0: B,B,A,A then ks1)
        i32x4 a0[2], b0[2], a1[2], b1[2];
        b0[0] = *(const i32x4*)(Bb + bRow + 0 * 2048 + sA0);
        b0[1] = *(const i32x4*)(Bb + bRow + 1 * 2048 + sA0);
        a0[0] = *(const i32x4*)(Ab + aRow + 0 * 2048 + sA0);
        a0[1] = *(const i32x4*)(Ab + aRow + 1 * 2048 + sA0);
        b1[0] = *(const i32x4*)(Bb + bRow + 0 * 2048 + sA1);
        b1[1] = *(const i32x4*)(Bb + bRow + 1 * 2048 + sA1);
        a1[0] = *(const i32x4*)(Ab + aRow + 0 * 2048 + sA1);
        a1[1] = *(const i32x4*)(Ab + aRow + 1 * 2048 + sA1);

        __builtin_amdgcn_s_setprio(1);
        #pragma unroll
        for (int mi = 0; mi < 2; ++mi)
            #pragma unroll
            for (int ni = 0; ni < 2; ++ni)
                acc[mi][ni] = __builtin_amdgcn_mfma_i32_32x32x32_i8(
                    a0[mi], b0[ni], acc[mi][ni], 0, 0, 0);
        #pragma unroll
        for (int mi = 0; mi < 2; ++mi)
            #pragma unroll
            for (int ni = 0; ni < 2; ++ni)
                acc[mi][ni] = __builtin_amdgcn_mfma_i32_32x32x32_i8(
                    a1[mi], b1[ni], acc[mi][ni], 0, 0, 0);
        __builtin_amdgcn_s_setprio(0);
        __builtin_amdgcn_sched_barrier(0);

        // boundary: vmcnt ladder (certify tile t+1) + barrier (r16-identical)
        if (t <= NT - 4)      { asm volatile("s_waitcnt vmcnt(4)" ::: "memory"); }
        else if (t == NT - 3) { asm volatile("s_waitcnt vmcnt(2)" ::: "memory"); }
        else                  { asm volatile("s_waitcnt vmcnt(0)" ::: "memory"); }
        __builtin_amdgcn_s_barrier();
        __builtin_amdgcn_sched_barrier(0);
    }

    // ---- epilogue: out = acc * sinv[row] + bias[col] ----
    // C/D 32x32 (m74/m101, dtype-indep): col=l&31, row=(r&3)+8*(r>>2)+4*l5
    float bv[2];
    int   cols[2];
    #pragma unroll
    for (int ni = 0; ni < 2; ++ni) {
        cols[ni] = (int)bcol + wc * 64 + ni * 32 + l31;
        bv[ni] = bias[cols[ni]];
    }
    #pragma unroll
    for (int mi = 0; mi < 2; ++mi) {
        #pragma unroll
        for (int r = 0; r < 16; ++r) {
            const size_t grow = (size_t)brow + wr * 64 + mi * 32
                              + (r & 3) + 8 * (r >> 2) + 4 * l5;
            const float sv = sinv[grow];
            #pragma unroll
            for (int ni = 0; ni < 2; ++ni)
                out[grow * N_DIM + cols[ni]] = (float)acc[mi][ni][r] * sv + bv[ni];
        }
    }
}

// ---------- fallback (only if workspace too small): correct but slow ----------

__global__ void naive_kernel(const float* __restrict__ x, const float* __restrict__ w,
                             const float* __restrict__ bias, float* __restrict__ out) {
    long long o = (long long)blockIdx.x * blockDim.x + threadIdx.x;
    if (o >= (long long)M_DIM * N_DIM) return;
    int row = (int)(o / N_DIM), col = (int)(o % N_DIM);
    float s = 0.0f;
    const float* xr = x + (size_t)row * K_DIM;
    const float* wr = w + (size_t)col * K_DIM;
    for (int k = 0; k < K_DIM; ++k) {
        float wv = wr[k];
        s += (wv > 0.0f) ? xr[k] : ((wv < 0.0f) ? -xr[k] : 0.0f);
    }
    out[o] = s + bias[col];
}

// ---------- launch ----------

extern "C" void kernel_launch(void* const* d_in, const int* in_sizes, int n_in,
                              void* d_out, int out_size, void* d_ws, size_t ws_size,
                              hipStream_t stream) {
    const float* x    = (const float*)d_in[0];
    const float* w    = (const float*)d_in[1];
    const float* bias = (const float*)d_in[2];
    float* out        = (float*)d_out;

    const size_t xq_bytes = (size_t)M_DIM * K_DIM;        // 33.6 MB
    const size_t wq_bytes = (size_t)N_DIM * K_DIM;        // 45.1 MB
    const size_t si_bytes = (size_t)M_DIM * sizeof(float);

    if (ws_size >= xq_bytes + wq_bytes + si_bytes) {
        int8_t* xq   = (int8_t*)d_ws;
        int8_t* wq   = (int8_t*)((char*)d_ws + xq_bytes);
        float*  sinv = (float*)((char*)d_ws + xq_bytes + wq_bytes);

        quant_x_kernel<<<M_DIM / 4, 256, 0, stream>>>(x, xq, sinv);
        const long long n16 = ((long long)N_DIM * K_DIM) / 16;
        sign_w_kernel<<<2048, 256, 0, stream>>>(w, wq, n16);

        const int lds_bytes = NRING * 2 * BUF;   // 131072
        hipFuncSetAttribute(reinterpret_cast<const void*>(ternary_gemm_i8),
                            hipFuncAttributeMaxDynamicSharedMemorySize, lds_bytes);
        ternary_gemm_i8<<<NWG, 1024, lds_bytes, stream>>>(xq, wq, bias, sinv, out);
    } else {
        const long long total = (long long)M_DIM * N_DIM;
        naive_kernel<<<(int)((total + 255) / 256), 256, 0, stream>>>(x, w, bias, out);
    }
}

// Round 19
// 468.139 us; speedup vs baseline: 3.5210x; 1.0842x over previous
//
#include <hip/hip_runtime.h>
#include <stdint.h>

#define M_DIM 8192
#define N_DIM 11008
#define K_DIM 4096

#define BM 256
#define BN 256
#define BKS 128                  // super-tile K-depth (2x64)
#define NS (K_DIM / BKS)         // 32 super-tiles
#define GRID_M (M_DIM / BM)      // 32
#define GRID_N (N_DIM / BN)      // 43
#define NWG (GRID_M * GRID_N)    // 1376 (divisible by 8)

#define HBUF 16384               // one 64-K half image per matrix (r16 BUF)
#define SBUF (2 * HBUF)          // 32 KiB super-tile buffer per matrix
// LDS: 2 super-slots x 2 matrices x 32KB = 131072 B (128 KiB)

typedef int i32x4 __attribute__((ext_vector_type(4)));

__device__ __forceinline__ void gload16(const int8_t* src, int8_t* dst) {
    __builtin_amdgcn_global_load_lds(
        (const __attribute__((address_space(1))) uint32_t*)src,
        (__attribute__((address_space(3))) uint32_t*)dst, 16, 0, 0);
}

// ---------- pre-pass 1: per-row (token) absmax quant of x -> i8 + inv scale ----------

__global__ __launch_bounds__(256) void quant_x_kernel(
    const float* __restrict__ x, int8_t* __restrict__ xq, float* __restrict__ sinv)
{
    const int wave = blockIdx.x * 4 + (threadIdx.x >> 6);
    const int lane = threadIdx.x & 63;
    const float* row = x + (size_t)wave * K_DIM;

    float4 v[16];
    float mx = 0.0f;
    #pragma unroll
    for (int j = 0; j < 16; ++j) {
        v[j] = *(const float4*)(row + (j * 64 + lane) * 4);
        mx = fmaxf(mx, fmaxf(fmaxf(fabsf(v[j].x), fabsf(v[j].y)),
                             fmaxf(fabsf(v[j].z), fabsf(v[j].w))));
    }
    #pragma unroll
    for (int off = 32; off > 0; off >>= 1)
        mx = fmaxf(mx, __shfl_xor(mx, off));
    if (mx < 1e-30f) mx = 1e-30f;
    const float s = 127.0f / mx;

    int8_t* orow = xq + (size_t)wave * K_DIM;
    #pragma unroll
    for (int j = 0; j < 16; ++j) {
        int a = (int)__builtin_rintf(v[j].x * s);
        int b = (int)__builtin_rintf(v[j].y * s);
        int c = (int)__builtin_rintf(v[j].z * s);
        int d = (int)__builtin_rintf(v[j].w * s);
        uint32_t p = (uint32_t)(a & 0xFF) | ((uint32_t)(b & 0xFF) << 8) |
                     ((uint32_t)(c & 0xFF) << 16) | ((uint32_t)(d & 0xFF) << 24);
        *(uint32_t*)(orow + (j * 64 + lane) * 4) = p;
    }
    if (lane == 0) sinv[wave] = mx / 127.0f;
}

// ---------- pre-pass 2: f32 w -> sign(w) in i8 (exact {-1,0,+1}) ----------

__global__ __launch_bounds__(256) void sign_w_kernel(
    const float* __restrict__ w, int8_t* __restrict__ wq, long long n16)
{
    long long i = (long long)blockIdx.x * blockDim.x + threadIdx.x;
    const long long stride = (long long)gridDim.x * blockDim.x;
    for (; i < n16; i += stride) {
        const float* src = w + i * 16;
        uint32_t pk[4];
        #pragma unroll
        for (int q = 0; q < 4; ++q) {
            float4 f = *(const float4*)(src + q * 4);
            int a = (f.x > 0.f) ? 1 : ((f.x < 0.f) ? -1 : 0);
            int b = (f.y > 0.f) ? 1 : ((f.y < 0.f) ? -1 : 0);
            int c = (f.z > 0.f) ? 1 : ((f.z < 0.f) ? -1 : 0);
            int d = (f.w > 0.f) ? 1 : ((f.w < 0.f) ? -1 : 0);
            pk[q] = (uint32_t)(a & 0xFF) | ((uint32_t)(b & 0xFF) << 8) |
                    ((uint32_t)(c & 0xFF) << 16) | ((uint32_t)(d & 0xFF) << 24);
        }
        *(i32x4*)(wq + i * 16) = (i32x4){(int)pk[0], (int)pk[1], (int)pk[2], (int)pk[3]};
    }
}

// ---------- main GEMM (i8): 256x256, 16 waves, SUPER-TILE BK=128, RING-2.
// r18 post-mortem: 32x32x32 regressed (bank conflicts 4.5e7 + coarser MFMA
// blocking) -> reverted to r16's proven 16x16x64 shape/swizzle (0 conflicts).
// This round halves the per-tile sync overhead: one body = 2 K-tiles (BK=128
// super-tile), ring-2 double buffer (2 x 64KB = 128KB LDS), ONE vmcnt +
// ONE barrier per 2 K-tiles, and the stage DMA issues at body START so its
// latency hides under ~2000 cy of body compute.
//
// body(S) [cur slot c = S&1]:
//   stage(S+1) -> slot c^1        (4 gloads; first, for max latency slack)
//   reads half0 (8 b128) ; MFMA half0 (16)
//   reads half1 (8 b128) ; MFMA half1 (16)   (one frag set live: 124 regs,
//                                             4 waves/SIMD preserved)
//   vmcnt(0)                      (waits own st(S+1), issued ~2000 cy ago)
//   s_barrier
// Hazards: RAW st(S+1)->reads at body(S+1): boundary(S) vmcnt(0)+barrier (all
// waves). WAR stage(S+1) writes slot c^1 = slot read by body(S-1), whose
// reads completed before boundary(S-1) barrier (operand dependence). Ring-2
// valid because the write targets the OTHER slot than the one being read.
// Prologue: stage(0); vmcnt(0); barrier (one exposed DMA wait, ~500 cy once).
// Frag addressing per 16KB half-image: byte-identical to r16 (verified,
// 0 conflicts, absmax 3.75).

__global__ __launch_bounds__(1024, 4) void ternary_gemm_i8(
    const int8_t* __restrict__ A, const int8_t* __restrict__ B,
    const float* __restrict__ bias, const float* __restrict__ sinv,
    float* __restrict__ out)
{
    extern __shared__ int8_t lds[];
    int8_t* As = lds;                   // [2][SBUF]
    int8_t* Bs = lds + 2 * SBUF;        // [2][SBUF]

    const int tid  = threadIdx.x;
    const int lane = tid & 63;
    const int wid  = tid >> 6;        // 0..15
    const int wr   = wid >> 2;        // 0..3  (64-row slab)
    const int wc   = wid & 3;         // 0..3  (64-col slab)
    const int l15  = lane & 15;
    const int l4   = lane >> 4;       // 0..3

    // T1: bijective XCD swizzle (NWG % 8 == 0), bn-minor for A-panel L2 reuse
    const int bid = blockIdx.x;
    const int swz = (bid & 7) * (NWG / 8) + (bid >> 3);
    const int bm  = swz / GRID_N;
    const int bn  = swz % GRID_N;
    const long brow = (long)bm * BM;
    const long bcol = (long)bn * BN;

    // ---- staging addressing (r16-identical per half): row = tid>>2, LDS dest
    // linear (tid*16), global src slot inverse-swizzled ----
    const int rowt = tid >> 2;                        // 0..255
    const int ssrc = (tid & 3) ^ ((tid >> 3) & 3);
    const int8_t* pA = A + (size_t)(brow + rowt) * K_DIM + ssrc * 16;
    const int8_t* pB = B + (size_t)(bcol + rowt) * K_DIM + ssrc * 16;

    // stage super-tile S into slot sl: 2 halves x (A,B), 4 gloads
    auto stageS = [&](int S, int sl) {
        #pragma unroll
        for (int h = 0; h < 2; ++h) {
            const size_t koff = (size_t)S * BKS + (size_t)h * 64;
            gload16(pA + koff, As + sl * SBUF + h * HBUF + tid * 16);
            gload16(pB + koff, Bs + sl * SBUF + h * HBUF + tid * 16);
        }
    };

    // ---- fragment read addressing (r16-verified swizzle, per half-image) ----
    const int slot = l4 ^ ((l15 >> 1) & 3);
    const int aOff = (wr * 64 + l15) * 64 + slot * 16;   // + m*1024 (m*16 rows)
    const int bOff = (wc * 64 + l15) * 64 + slot * 16;   // + n*1024

    i32x4 acc[4][4];
    #pragma unroll
    for (int m = 0; m < 4; ++m)
        #pragma unroll
        for (int n = 0; n < 4; ++n) acc[m][n] = (i32x4){0, 0, 0, 0};

    // ---- prologue: stage super-tile 0; drain; barrier ----
    stageS(0, 0);
    asm volatile("s_waitcnt vmcnt(0)" ::: "memory");
    __builtin_amdgcn_s_barrier();
    __builtin_amdgcn_sched_barrier(0);

    for (int S = 0; S < NS; ++S) {
        const int c = S & 1;
        const int8_t* Ac = As + c * SBUF;
        const int8_t* Bc = Bs + c * SBUF;

        // stage next super-tile first (DMA latency hides under this body)
        if (S + 1 < NS) stageS(S + 1, c ^ 1);

        #pragma unroll
        for (int h = 0; h < 2; ++h) {
            const int8_t* Ah = Ac + h * HBUF;
            const int8_t* Bh = Bc + h * HBUF;
            i32x4 ar[4], br[4];
            #pragma unroll
            for (int n = 0; n < 4; ++n)
                br[n] = *(const i32x4*)(Bh + n * 1024 + bOff);
            #pragma unroll
            for (int m = 0; m < 4; ++m)
                ar[m] = *(const i32x4*)(Ah + m * 1024 + aOff);

            __builtin_amdgcn_s_setprio(1);
            #pragma unroll
            for (int m = 0; m < 4; ++m)
                #pragma unroll
                for (int n = 0; n < 4; ++n)
                    acc[m][n] = __builtin_amdgcn_mfma_i32_16x16x64_i8(
                        ar[m], br[n], acc[m][n], 0, 0, 0);
            __builtin_amdgcn_s_setprio(0);
        }
        __builtin_amdgcn_sched_barrier(0);

        // boundary: certify st(S+1) (only in-flight VMEM) + barrier
        asm volatile("s_waitcnt vmcnt(0)" ::: "memory");
        __builtin_amdgcn_s_barrier();
        __builtin_amdgcn_sched_barrier(0);
    }

    // ---- epilogue: out = acc * sinv[row] + bias[col] ----
    // C/D layout (dtype-independent, m121-128): col=lane&15, row=(lane>>4)*4+reg
    int   cols[4];
    float bv[4];
    #pragma unroll
    for (int n = 0; n < 4; ++n) {
        cols[n] = (int)bcol + wc * 64 + n * 16 + l15;
        bv[n] = bias[cols[n]];
    }
    #pragma unroll
    for (int m = 0; m < 4; ++m) {
        const size_t row0 = (size_t)brow + wr * 64 + m * 16 + l4 * 4;
        float s0 = sinv[row0], s1 = sinv[row0 + 1], s2 = sinv[row0 + 2], s3 = sinv[row0 + 3];
        #pragma unroll
        for (int n = 0; n < 4; ++n) {
            out[(row0 + 0) * N_DIM + cols[n]] = (float)acc[m][n][0] * s0 + bv[n];
            out[(row0 + 1) * N_DIM + cols[n]] = (float)acc[m][n][1] * s1 + bv[n];
            out[(row0 + 2) * N_DIM + cols[n]] = (float)acc[m][n][2] * s2 + bv[n];
            out[(row0 + 3) * N_DIM + cols[n]] = (float)acc[m][n][3] * s3 + bv[n];
        }
    }
}

// ---------- fallback (only if workspace too small): correct but slow ----------

__global__ void naive_kernel(const float* __restrict__ x, const float* __restrict__ w,
                             const float* __restrict__ bias, float* __restrict__ out) {
    long long o = (long long)blockIdx.x * blockDim.x + threadIdx.x;
    if (o >= (long long)M_DIM * N_DIM) return;
    int row = (int)(o / N_DIM), col = (int)(o % N_DIM);
    float s = 0.0f;
    const float* xr = x + (size_t)row * K_DIM;
    const float* wr = w + (size_t)col * K_DIM;
    for (int k = 0; k < K_DIM; ++k) {
        float wv = wr[k];
        s += (wv > 0.0f) ? xr[k] : ((wv < 0.0f) ? -xr[k] : 0.0f);
    }
    out[o] = s + bias[col];
}

// ---------- launch ----------

extern "C" void kernel_launch(void* const* d_in, const int* in_sizes, int n_in,
                              void* d_out, int out_size, void* d_ws, size_t ws_size,
                              hipStream_t stream) {
    const float* x    = (const float*)d_in[0];
    const float* w    = (const float*)d_in[1];
    const float* bias = (const float*)d_in[2];
    float* out        = (float*)d_out;

    const size_t xq_bytes = (size_t)M_DIM * K_DIM;        // 33.6 MB
    const size_t wq_bytes = (size_t)N_DIM * K_DIM;        // 45.1 MB
    const size_t si_bytes = (size_t)M_DIM * sizeof(float);

    if (ws_size >= xq_bytes + wq_bytes + si_bytes) {
        int8_t* xq   = (int8_t*)d_ws;
        int8_t* wq   = (int8_t*)((char*)d_ws + xq_bytes);
        float*  sinv = (float*)((char*)d_ws + xq_bytes + wq_bytes);

        quant_x_kernel<<<M_DIM / 4, 256, 0, stream>>>(x, xq, sinv);
        const long long n16 = ((long long)N_DIM * K_DIM) / 16;
        sign_w_kernel<<<2048, 256, 0, stream>>>(w, wq, n16);

        const int lds_bytes = 4 * SBUF;   // 131072
        hipFuncSetAttribute(reinterpret_cast<const void*>(ternary_gemm_i8),
                            hipFuncAttributeMaxDynamicSharedMemorySize, lds_bytes);
        ternary_gemm_i8<<<NWG, 1024, lds_bytes, stream>>>(xq, wq, bias, sinv, out);
    } else {
        const long long total = (long long)M_DIM * N_DIM;
        naive_kernel<<<(int)((total + 255) / 256), 256, 0, stream>>>(x, w, bias, out);
    }
}

// Round 20
// 459.812 us; speedup vs baseline: 3.5847x; 1.0181x over previous
//
#include <hip/hip_runtime.h>
#include <stdint.h>

#define M_DIM 8192
#define N_DIM 11008
#define K_DIM 4096

#define BM 256
#define BN 256
#define BK 64                    // i8: 64 B per row per tile
#define NT (K_DIM / BK)          // 64 K-tiles
#define GRID_M (M_DIM / BM)      // 32
#define GRID_N (N_DIM / BN)      // 43
#define NWG (GRID_M * GRID_N)    // 1376 (divisible by 8)

#define BUF (BM * BK)            // 16384 B per tile-buffer per matrix
#define NRING 4                  // ring-4: LDS = 4*2*16384 = 131072 B (128 KiB)

typedef int i32x4 __attribute__((ext_vector_type(4)));

__device__ __forceinline__ void gload16(const int8_t* src, int8_t* dst) {
    __builtin_amdgcn_global_load_lds(
        (const __attribute__((address_space(1))) uint32_t*)src,
        (__attribute__((address_space(3))) uint32_t*)dst, 16, 0, 0);
}

// ---------- merged pre-pass: one launch, two jobs ----------
// blocks [0, 2048):   per-row absmax quant of x -> i8 + inv scale (4 waves/blk,
//                     8192 waves = 8192 rows exactly)
// blocks [2048, 4096): f32 w -> sign(w) in i8 (grid-stride over 16-elem vecs)
// Both BW-bound; concurrent execution shares HBM BW, saves a launch gap.

__global__ __launch_bounds__(256) void prepass_kernel(
    const float* __restrict__ x, int8_t* __restrict__ xq, float* __restrict__ sinv,
    const float* __restrict__ w, int8_t* __restrict__ wq, long long n16)
{
    if (blockIdx.x < 2048) {
        const int wave = blockIdx.x * 4 + (threadIdx.x >> 6);
        const int lane = threadIdx.x & 63;
        const float* row = x + (size_t)wave * K_DIM;

        float4 v[16];
        float mx = 0.0f;
        #pragma unroll
        for (int j = 0; j < 16; ++j) {
            v[j] = *(const float4*)(row + (j * 64 + lane) * 4);
            mx = fmaxf(mx, fmaxf(fmaxf(fabsf(v[j].x), fabsf(v[j].y)),
                                 fmaxf(fabsf(v[j].z), fabsf(v[j].w))));
        }
        #pragma unroll
        for (int off = 32; off > 0; off >>= 1)
            mx = fmaxf(mx, __shfl_xor(mx, off));
        if (mx < 1e-30f) mx = 1e-30f;
        const float s = 127.0f / mx;

        int8_t* orow = xq + (size_t)wave * K_DIM;
        #pragma unroll
        for (int j = 0; j < 16; ++j) {
            int a = (int)__builtin_rintf(v[j].x * s);
            int b = (int)__builtin_rintf(v[j].y * s);
            int c = (int)__builtin_rintf(v[j].z * s);
            int d = (int)__builtin_rintf(v[j].w * s);
            uint32_t p = (uint32_t)(a & 0xFF) | ((uint32_t)(b & 0xFF) << 8) |
                         ((uint32_t)(c & 0xFF) << 16) | ((uint32_t)(d & 0xFF) << 24);
            *(uint32_t*)(orow + (j * 64 + lane) * 4) = p;
        }
        if (lane == 0) sinv[wave] = mx / 127.0f;
    } else {
        long long i = (long long)(blockIdx.x - 2048) * blockDim.x + threadIdx.x;
        const long long stride = 2048LL * blockDim.x;
        for (; i < n16; i += stride) {
            const float* src = w + i * 16;
            uint32_t pk[4];
            #pragma unroll
            for (int q = 0; q < 4; ++q) {
                float4 f = *(const float4*)(src + q * 4);
                int a = (f.x > 0.f) ? 1 : ((f.x < 0.f) ? -1 : 0);
                int b = (f.y > 0.f) ? 1 : ((f.y < 0.f) ? -1 : 0);
                int c = (f.z > 0.f) ? 1 : ((f.z < 0.f) ? -1 : 0);
                int d = (f.w > 0.f) ? 1 : ((f.w < 0.f) ? -1 : 0);
                pk[q] = (uint32_t)(a & 0xFF) | ((uint32_t)(b & 0xFF) << 8) |
                        ((uint32_t)(c & 0xFF) << 16) | ((uint32_t)(d & 0xFF) << 24);
            }
            *(i32x4*)(wq + i * 16) = (i32x4){(int)pk[0], (int)pk[1], (int)pk[2], (int)pk[3]};
        }
    }
}

// ---------- main GEMM (i8): 256x256, BK=64, 16 waves, RING-4 (r16, proven
// best: 386us GEMM, 0 conflicts, absmax 3.75). Only change vs r16: frag reads
// issued in CONSUMPTION ORDER (B[0..3] then A[0..3]) — r16 issued br[3] last
// but MFMA #4 consumes it, forcing all 8 reads to land before 1/4 of compute;
// B-first lets the compiler's fine-grained lgkm start MFMA after read 5.
//
// Constraint-box summary (r8-r19): VRF 512 regs/SIMD pins geometry:
//   4 waves/SIMD -> <=128 regs -> 64x64/wave -> 4x LDS amplification ->
//   DS leg 1536 cy/tile (85 B/cy measured rate) > MFMA 1306 -> LDS-BW-bound.
//   2 waves/SIMD -> 128x64/wave (amp 3, compute-bound) but overlap fails.
// Cross-tile frag pipelining needs +16-32 regs -> breaks the 128 cap.
// r16's 2412 cy/tile = 1536 DS + partial overlap + sync; 11 structural
// variants all land 2400-2500. This is the box's floor.

__global__ __launch_bounds__(1024, 4) void ternary_gemm_i8(
    const int8_t* __restrict__ A, const int8_t* __restrict__ B,
    const float* __restrict__ bias, const float* __restrict__ sinv,
    float* __restrict__ out)
{
    extern __shared__ int8_t lds[];
    int8_t* As = lds;                   // [NRING][BUF]
    int8_t* Bs = lds + NRING * BUF;     // [NRING][BUF]

    const int tid  = threadIdx.x;
    const int lane = tid & 63;
    const int wid  = tid >> 6;        // 0..15
    const int wr   = wid >> 2;        // 0..3  (64-row slab)
    const int wc   = wid & 3;         // 0..3  (64-col slab)
    const int l15  = lane & 15;
    const int l4   = lane >> 4;       // 0..3

    // T1: bijective XCD swizzle (NWG % 8 == 0), bn-minor for A-panel L2 reuse
    const int bid = blockIdx.x;
    const int swz = (bid & 7) * (NWG / 8) + (bid >> 3);
    const int bm  = swz / GRID_N;
    const int bn  = swz % GRID_N;
    const long brow = (long)bm * BM;
    const long bcol = (long)bn * BN;

    // ---- staging addressing: 1024 threads cover 256 rows x 4 slots;
    // row = tid>>2, LDS dest linear (tid*16), global src slot inverse-swizzled
    const int rowt = tid >> 2;                        // 0..255
    const int ssrc = (tid & 3) ^ ((tid >> 3) & 3);
    const int8_t* pA = A + (size_t)(brow + rowt) * K_DIM + ssrc * 16;
    const int8_t* pB = B + (size_t)(bcol + rowt) * K_DIM + ssrc * 16;

    auto stageAB = [&](int t, int bslot) {
        gload16(pA + (size_t)t * BK, As + bslot * BUF + tid * 16);
        gload16(pB + (size_t)t * BK, Bs + bslot * BUF + tid * 16);
    };

    // ---- fragment read addressing (r6-verified swizzle) ----
    const int slot = l4 ^ ((l15 >> 1) & 3);
    const int aOff = (wr * 64 + l15) * 64 + slot * 16;   // + m*1024 (m*16 rows)
    const int bOff = (wc * 64 + l15) * 64 + slot * 16;   // + n*1024

    i32x4 acc[4][4];
    #pragma unroll
    for (int m = 0; m < 4; ++m)
        #pragma unroll
        for (int n = 0; n < 4; ++n) acc[m][n] = (i32x4){0, 0, 0, 0};

    // ---- prologue: stage tiles 0,1,2; vmcnt(4) [tile 0 landed]; barrier ----
    stageAB(0, 0); stageAB(1, 1); stageAB(2, 2);
    asm volatile("s_waitcnt vmcnt(4)" ::: "memory");
    __builtin_amdgcn_s_barrier();
    __builtin_amdgcn_sched_barrier(0);

    for (int t = 0; t < NT; ++t) {
        const int b = t & 3;

        // 8 frag reads, CONSUMPTION ORDER: br[0..3] then ar[0..3]
        i32x4 ar[4], br[4];
        #pragma unroll
        for (int n = 0; n < 4; ++n)
            br[n] = *(const i32x4*)(Bs + b * BUF + n * 1024 + bOff);
        #pragma unroll
        for (int m = 0; m < 4; ++m)
            ar[m] = *(const i32x4*)(As + b * BUF + m * 1024 + aOff);

        // stage(t+3) -> slot (t-1)%4 (WAR-safe: readers done pre-boundary(t-1))
        if (t + 3 < NT) stageAB(t + 3, (t + 3) & 3);

        __builtin_amdgcn_s_setprio(1);
        #pragma unroll
        for (int m = 0; m < 4; ++m)
            #pragma unroll
            for (int n = 0; n < 4; ++n)
                acc[m][n] = __builtin_amdgcn_mfma_i32_16x16x64_i8(ar[m], br[n], acc[m][n], 0, 0, 0);
        __builtin_amdgcn_s_setprio(0);
        __builtin_amdgcn_sched_barrier(0);

        // boundary: vmcnt ladder (certify tile t+1) + barrier
        if (t <= NT - 4)      { asm volatile("s_waitcnt vmcnt(4)" ::: "memory"); }
        else if (t == NT - 3) { asm volatile("s_waitcnt vmcnt(2)" ::: "memory"); }
        else                  { asm volatile("s_waitcnt vmcnt(0)" ::: "memory"); }
        __builtin_amdgcn_s_barrier();
        __builtin_amdgcn_sched_barrier(0);
    }

    // ---- epilogue: out = acc * sinv[row] + bias[col] ----
    // C/D layout (dtype-independent, m121-128): col=lane&15, row=(lane>>4)*4+reg
    int   cols[4];
    float bv[4];
    #pragma unroll
    for (int n = 0; n < 4; ++n) {
        cols[n] = (int)bcol + wc * 64 + n * 16 + l15;
        bv[n] = bias[cols[n]];
    }
    #pragma unroll
    for (int m = 0; m < 4; ++m) {
        const size_t row0 = (size_t)brow + wr * 64 + m * 16 + l4 * 4;
        float s0 = sinv[row0], s1 = sinv[row0 + 1], s2 = sinv[row0 + 2], s3 = sinv[row0 + 3];
        #pragma unroll
        for (int n = 0; n < 4; ++n) {
            out[(row0 + 0) * N_DIM + cols[n]] = (float)acc[m][n][0] * s0 + bv[n];
            out[(row0 + 1) * N_DIM + cols[n]] = (float)acc[m][n][1] * s1 + bv[n];
            out[(row0 + 2) * N_DIM + cols[n]] = (float)acc[m][n][2] * s2 + bv[n];
            out[(row0 + 3) * N_DIM + cols[n]] = (float)acc[m][n][3] * s3 + bv[n];
        }
    }
}

// ---------- fallback (only if workspace too small): correct but slow ----------

__global__ void naive_kernel(const float* __restrict__ x, const float* __restrict__ w,
                             const float* __restrict__ bias, float* __restrict__ out) {
    long long o = (long long)blockIdx.x * blockDim.x + threadIdx.x;
    if (o >= (long long)M_DIM * N_DIM) return;
    int row = (int)(o / N_DIM), col = (int)(o % N_DIM);
    float s = 0.0f;
    const float* xr = x + (size_t)row * K_DIM;
    const float* wr = w + (size_t)col * K_DIM;
    for (int k = 0; k < K_DIM; ++k) {
        float wv = wr[k];
        s += (wv > 0.0f) ? xr[k] : ((wv < 0.0f) ? -xr[k] : 0.0f);
    }
    out[o] = s + bias[col];
}

// ---------- launch ----------

extern "C" void kernel_launch(void* const* d_in, const int* in_sizes, int n_in,
                              void* d_out, int out_size, void* d_ws, size_t ws_size,
                              hipStream_t stream) {
    const float* x    = (const float*)d_in[0];
    const float* w    = (const float*)d_in[1];
    const float* bias = (const float*)d_in[2];
    float* out        = (float*)d_out;

    const size_t xq_bytes = (size_t)M_DIM * K_DIM;        // 33.6 MB
    const size_t wq_bytes = (size_t)N_DIM * K_DIM;        // 45.1 MB
    const size_t si_bytes = (size_t)M_DIM * sizeof(float);

    if (ws_size >= xq_bytes + wq_bytes + si_bytes) {
        int8_t* xq   = (int8_t*)d_ws;
        int8_t* wq   = (int8_t*)((char*)d_ws + xq_bytes);
        float*  sinv = (float*)((char*)d_ws + xq_bytes + wq_bytes);

        const long long n16 = ((long long)N_DIM * K_DIM) / 16;
        prepass_kernel<<<4096, 256, 0, stream>>>(x, xq, sinv, w, wq, n16);

        const int lds_bytes = NRING * 2 * BUF;   // 131072
        hipFuncSetAttribute(reinterpret_cast<const void*>(ternary_gemm_i8),
                            hipFuncAttributeMaxDynamicSharedMemorySize, lds_bytes);
        ternary_gemm_i8<<<NWG, 1024, lds_bytes, stream>>>(xq, wq, bias, sinv, out);
    } else {
        const long long total = (long long)M_DIM * N_DIM;
        naive_kernel<<<(int)((total + 255) / 256), 256, 0, stream>>>(x, w, bias, out);
    }
}